// Round 1
// baseline (175.421 us; speedup 1.0000x reference)
//
#include <hip/hip_runtime.h>

#define NK 512
#define NB 4
#define NC 256
#define NH 200
#define NW 200
#define RSCALE 0.0625f

// One block per (roi k, channel c). 512 threads.
// Phase 1: 44 threads compute per-dim sample coords (22 x-samples, 22 y-samples).
// Phase 2: 484 threads compute one bilinear sample each -> LDS.
// Phase 3: 121 threads average 2x2 samples -> 11x11 pooled bins.
// Phase 4: 25 threads 3x3/stride2 max-pool -> out (k, c, 5, 5).
__global__ __launch_bounds__(512) void roi_align_maxpool(
    const float* __restrict__ feat,   // (B, C, H, W)
    const float* __restrict__ rois,   // (K, 5): b, x1, y1, x2, y2
    float* __restrict__ out)          // (K, C, 5, 5)
{
    __shared__ int   s_lo[2][22];   // [0]=x, [1]=y
    __shared__ int   s_hi[2][22];
    __shared__ float s_fr[2][22];
    __shared__ float s_va[2][22];
    __shared__ float s_samp[22][23]; // [iy][ix], padded
    __shared__ float s_pool[11][12]; // padded

    const int blk = blockIdx.x;
    const int k = blk % NK;          // roi fastest -> co-resident blocks share channel planes in L2
    const int c = blk / NK;
    const int t = threadIdx.x;

    // Wave-uniform roi read (broadcast, L1/L2 hit)
    const float r0  = rois[k * 5 + 0];
    const float rx1 = rois[k * 5 + 1] * RSCALE;
    const float ry1 = rois[k * 5 + 2] * RSCALE;
    const float rx2 = rois[k * 5 + 3] * RSCALE;
    const float ry2 = rois[k * 5 + 4] * RSCALE;
    const int   b   = (int)r0;
    const float bin_w = fmaxf(rx2 - rx1, 1.0f) / 11.0f;
    const float bin_h = fmaxf(ry2 - ry1, 1.0f) / 11.0f;

    if (t < 44) {
        const int d = t / 22;        // 0 = x dim, 1 = y dim
        const int i = t % 22;        // i = bin*2 + sub-sample
        const float start = d ? ry1 : rx1;
        const float bs    = d ? bin_h : bin_w;
        const int   lim   = d ? NH : NW;
        const float p = (float)(i >> 1);
        const float g = ((float)(i & 1) + 0.5f) / 2.0f;   // (s+0.5)/S, S=2
        float cv = start + (p + g) * bs;                  // same expr order as reference
        const float va = (cv > -1.0f && cv < (float)lim) ? 1.0f : 0.0f;
        cv = fminf(fmaxf(cv, 0.0f), (float)(lim - 1));
        const int lo = (int)floorf(cv);
        s_lo[d][i] = lo;
        s_hi[d][i] = min(lo + 1, lim - 1);
        s_fr[d][i] = cv - (float)lo;
        s_va[d][i] = va;
    }
    __syncthreads();

    if (t < 484) {
        const int iy = t / 22;
        const int ix = t % 22;
        const int xlo = s_lo[0][ix], xhi = s_hi[0][ix];
        const int ylo = s_lo[1][iy], yhi = s_hi[1][iy];
        const float lx = s_fr[0][ix], ly = s_fr[1][iy];
        const float hx = 1.0f - lx,  hy = 1.0f - ly;
        const float* fp = feat + (size_t)(b * NC + c) * (NH * NW);
        const float v00 = fp[ylo * NW + xlo];
        const float v01 = fp[ylo * NW + xhi];
        const float v10 = fp[yhi * NW + xlo];
        const float v11 = fp[yhi * NW + xhi];
        float v = hy * (hx * v00 + lx * v01) + ly * (hx * v10 + lx * v11);
        v *= s_va[0][ix] * s_va[1][iy];
        s_samp[iy][ix] = v;
    }
    __syncthreads();

    if (t < 121) {
        const int ph = t / 11, pw = t % 11;
        s_pool[ph][pw] = 0.25f * (s_samp[2*ph    ][2*pw] + s_samp[2*ph    ][2*pw+1] +
                                  s_samp[2*ph + 1][2*pw] + s_samp[2*ph + 1][2*pw+1]);
    }
    __syncthreads();

    if (t < 25) {
        const int oh = t / 5, ow = t % 5;
        float m = -INFINITY;
        #pragma unroll
        for (int dy = 0; dy < 3; ++dy)
            #pragma unroll
            for (int dx = 0; dx < 3; ++dx)
                m = fmaxf(m, s_pool[2*oh + dy][2*ow + dx]);
        out[(size_t)(k * NC + c) * 25 + oh * 5 + ow] = m;
    }
}

extern "C" void kernel_launch(void* const* d_in, const int* in_sizes, int n_in,
                              void* d_out, int out_size, void* d_ws, size_t ws_size,
                              hipStream_t stream) {
    const float* feat = (const float*)d_in[0];   // (4, 256, 200, 200) f32
    const float* rois = (const float*)d_in[1];   // (512, 5) f32
    float* out = (float*)d_out;                  // (512, 256, 5, 5) f32

    const int nblocks = NK * NC;                 // 131072
    roi_align_maxpool<<<nblocks, 512, 0, stream>>>(feat, rois, out);
}

// Round 2
// 71.323 us; speedup vs baseline: 2.4595x; 2.4595x over previous
//
#include <hip/hip_runtime.h>

#define NK 512
#define NC 256
#define NH 200
#define NW 200
#define RSCALE 0.0625f
#define GC 4   // channels per block

// One block per (roi k, 4-channel group). 512 threads.
// Phase 1: 44 threads build per-dim sample tables (22 x-samples, 22 y-samples).
// Phase 2: 484 threads = (ch, bin): each computes ONE pooled bin
//          (4 bilinear samples = 8 float2 row-pair loads) -> s_pool.
// Phase 3: 100 threads do 3x3/stride2 max-pool -> out (k, c, 5, 5), coalesced.
__global__ __launch_bounds__(512) void roi_align_maxpool(
    const float* __restrict__ feat,   // (B, C, H, W) f32
    const float* __restrict__ rois,   // (K, 5)
    float* __restrict__ out)          // (K, C, 5, 5)
{
    __shared__ int   s_xb[22];        // min(xlo, W-2)  -> float2 base col
    __shared__ float s_lx[22];        // adjusted x frac (1.0 when xlo==W-1)
    __shared__ float s_vx[22];        // x valid
    __shared__ int   s_yo0[22];       // ylo*W
    __shared__ int   s_yo1[22];       // yhi*W
    __shared__ float s_ly[22];
    __shared__ float s_vy[22];
    __shared__ float s_pool[GC][121];

    const int blk = blockIdx.x;
    const int k   = blk % NK;         // roi fastest: co-resident blocks share planes in L2
    const int cg  = blk / NK;
    const int t   = threadIdx.x;

    const float r0  = rois[k * 5 + 0];
    const float rx1 = rois[k * 5 + 1] * RSCALE;
    const float ry1 = rois[k * 5 + 2] * RSCALE;
    const float rx2 = rois[k * 5 + 3] * RSCALE;
    const float ry2 = rois[k * 5 + 4] * RSCALE;
    const int   b   = (int)r0;
    const float bin_w = fmaxf(rx2 - rx1, 1.0f) / 11.0f;
    const float bin_h = fmaxf(ry2 - ry1, 1.0f) / 11.0f;

    if (t < 44) {
        const int d = t / 22;         // 0 = x, 1 = y
        const int i = t % 22;         // sample index = bin*2 + sub
        const float start = d ? ry1 : rx1;
        const float bs    = d ? bin_h : bin_w;
        const int   lim   = d ? NH : NW;
        const float p = (float)(i >> 1);
        const float g = ((float)(i & 1) + 0.5f) / 2.0f;     // (s+0.5)/S, S=2
        float cv = start + (p + g) * bs;                    // same expr order as ref
        const float va = (cv > -1.0f && cv < (float)lim) ? 1.0f : 0.0f;
        cv = fminf(fmaxf(cv, 0.0f), (float)(lim - 1));
        const int lo = (int)floorf(cv);
        const int hi = min(lo + 1, lim - 1);
        const float fr = cv - (float)lo;
        if (d == 0) {
            // pair load at base=min(lo, W-2); if lo==W-1 the wanted value is
            // f[W-1]=pair.y and frac must become 1 so hx=0 kills pair.x.
            s_xb[i] = min(lo, NW - 2);
            s_lx[i] = (lo == NW - 1) ? 1.0f : fr;
            s_vx[i] = va;
        } else {
            s_yo0[i] = lo * NW;
            s_yo1[i] = hi * NW;
            s_ly[i] = fr;
            s_vy[i] = va;
        }
    }
    __syncthreads();

    if (t < 484) {
        const int ch  = t / 121;
        const int bin = t % 121;
        const int ph  = bin / 11, pw = bin % 11;
        const int ix0 = pw * 2, iy0 = ph * 2;

        const int   xb0 = s_xb[ix0],    xb1 = s_xb[ix0 + 1];
        const float lx0 = s_lx[ix0],    lx1 = s_lx[ix0 + 1];
        const float vx0 = s_vx[ix0],    vx1 = s_vx[ix0 + 1];
        const int   yo00 = s_yo0[iy0],  yo01 = s_yo1[iy0];
        const int   yo10 = s_yo0[iy0+1], yo11 = s_yo1[iy0+1];
        const float ly0 = s_ly[iy0],    ly1 = s_ly[iy0 + 1];
        const float vy0 = s_vy[iy0],    vy1 = s_vy[iy0 + 1];

        const float* fp = feat + (size_t)(b * NC + cg * GC + ch) * (NH * NW);

        // 8 independent 8B loads (row-pair per sample), all in flight together
        const float2 a00 = *(const float2*)(fp + yo00 + xb0);  // sample(x0,y0) lo row
        const float2 b00 = *(const float2*)(fp + yo01 + xb0);  //              hi row
        const float2 a10 = *(const float2*)(fp + yo00 + xb1);  // sample(x1,y0)
        const float2 b10 = *(const float2*)(fp + yo01 + xb1);
        const float2 a01 = *(const float2*)(fp + yo10 + xb0);  // sample(x0,y1)
        const float2 b01 = *(const float2*)(fp + yo11 + xb0);
        const float2 a11 = *(const float2*)(fp + yo10 + xb1);  // sample(x1,y1)
        const float2 b11 = *(const float2*)(fp + yo11 + xb1);

        const float hx0 = 1.0f - lx0, hx1 = 1.0f - lx1;
        const float hy0 = 1.0f - ly0, hy1 = 1.0f - ly1;

        const float s00 = hy0 * (hx0 * a00.x + lx0 * a00.y) + ly0 * (hx0 * b00.x + lx0 * b00.y);
        const float s10 = hy0 * (hx1 * a10.x + lx1 * a10.y) + ly0 * (hx1 * b10.x + lx1 * b10.y);
        const float s01 = hy1 * (hx0 * a01.x + lx0 * a01.y) + ly1 * (hx0 * b01.x + lx0 * b01.y);
        const float s11 = hy1 * (hx1 * a11.x + lx1 * a11.y) + ly1 * (hx1 * b11.x + lx1 * b11.y);

        const float sum = vy0 * (vx0 * s00 + vx1 * s10) + vy1 * (vx0 * s01 + vx1 * s11);
        s_pool[ch][bin] = 0.25f * sum;
    }
    __syncthreads();

    if (t < 100) {
        const int ch = t / 25;
        const int r  = t % 25;
        const int oh = r / 5, ow = r % 5;
        float m = -INFINITY;
        #pragma unroll
        for (int dy = 0; dy < 3; ++dy)
            #pragma unroll
            for (int dx = 0; dx < 3; ++dx)
                m = fmaxf(m, s_pool[ch][(2 * oh + dy) * 11 + (2 * ow + dx)]);
        // (k*NC + cg*GC + ch)*25 + oh*5+ow  ==  base + t  -> contiguous 100 floats
        out[((size_t)k * NC + cg * GC) * 25 + t] = m;
    }
}

extern "C" void kernel_launch(void* const* d_in, const int* in_sizes, int n_in,
                              void* d_out, int out_size, void* d_ws, size_t ws_size,
                              hipStream_t stream) {
    const float* feat = (const float*)d_in[0];   // (4, 256, 200, 200) f32
    const float* rois = (const float*)d_in[1];   // (512, 5) f32
    float* out = (float*)d_out;                  // (512, 256, 5, 5) f32

    const int nblocks = NK * (NC / GC);          // 32768
    roi_align_maxpool<<<nblocks, 512, 0, stream>>>(feat, rois, out);
}

// Round 3
// 63.521 us; speedup vs baseline: 2.7616x; 1.1228x over previous
//
#include <hip/hip_runtime.h>

#define NK 512
#define NC 256
#define NH 200
#define NW 200
#define RSCALE 0.0625f
#define GC 4   // channels per block

// One block per (roi k, 4-channel group). 512 threads.
// Phase 1: 22 threads build per-bin tables:
//   x-bin pw: base col xb[pw] (float4 window) + combined 4-wide x-weight W[pw][0..3]
//             (both x-sub-samples' bilinear weights, validity folded in)
//   y-bin ph: 4 row offsets yo[ph][r] (ylo0,yhi0,ylo1,yhi1)*NW + weights
//             wy[ph][r] = 0.25 * vy * (hy|ly)   (mean factor folded in)
// Phase 2: 484 threads = (ch, bin): pooled bin = sum_r wy[r] * dot4(load4(row_r), W)
//   -> 4 float4 gathers + 20 FMAs per bin.
// Phase 3: 100 threads 3x3/stride2 max-pool -> out, contiguous per block.
__global__ __launch_bounds__(512) void roi_align_maxpool(
    const float* __restrict__ feat,   // (B, C, H, W) f32
    const float* __restrict__ rois,   // (K, 5)
    float* __restrict__ out)          // (K, C, 5, 5)
{
    __shared__ int   s_xb[11];
    __shared__ float s_W [11][4];
    __shared__ int   s_yo[11][4];
    __shared__ float s_wy[11][4];
    __shared__ float s_pool[GC][121];

    const int blk = blockIdx.x;
    const int k   = blk % NK;         // roi fastest: co-resident blocks share planes in L2
    const int cg  = blk / NK;
    const int t   = threadIdx.x;

    const float r0  = rois[k * 5 + 0];
    const float rx1 = rois[k * 5 + 1] * RSCALE;
    const float ry1 = rois[k * 5 + 2] * RSCALE;
    const float rx2 = rois[k * 5 + 3] * RSCALE;
    const float ry2 = rois[k * 5 + 4] * RSCALE;
    const int   b   = (int)r0;
    const float bin_w = fmaxf(rx2 - rx1, 1.0f) / 11.0f;
    const float bin_h = fmaxf(ry2 - ry1, 1.0f) / 11.0f;

    if (t < 22) {
        const int d = t / 11;         // 0 = x, 1 = y
        const int pbin = t % 11;
        const float start = d ? ry1 : rx1;
        const float bs    = d ? bin_h : bin_w;
        const int   lim   = d ? NH : NW;
        const float p = (float)pbin;
        // sub-sample coords, same expression order as reference: start + (p+g)*bs
        const float g0 = (0.0f + 0.5f) / 2.0f;   // 0.25
        const float g1 = (1.0f + 0.5f) / 2.0f;   // 0.75
        float cv0 = start + (p + g0) * bs;
        float cv1 = start + (p + g1) * bs;
        const float va0 = (cv0 > -1.0f && cv0 < (float)lim) ? 1.0f : 0.0f;
        const float va1 = (cv1 > -1.0f && cv1 < (float)lim) ? 1.0f : 0.0f;
        cv0 = fminf(fmaxf(cv0, 0.0f), (float)(lim - 1));
        cv1 = fminf(fmaxf(cv1, 0.0f), (float)(lim - 1));
        const int lo0 = (int)floorf(cv0);
        const int lo1 = (int)floorf(cv1);
        const int hi0 = min(lo0 + 1, lim - 1);
        const int hi1 = min(lo1 + 1, lim - 1);
        const float fr0 = cv0 - (float)lo0;
        const float fr1 = cv1 - (float)lo1;
        if (d == 0) {
            // 4-col window covers both sub-samples: lo1 <= lo0+2 (bin_w<=2.85),
            // all relative indices land in [0,3] even at the W-1 clamp edge.
            const int xb = min(lo0, NW - 4);
            s_xb[pbin] = xb;
            s_W[pbin][0] = 0.0f; s_W[pbin][1] = 0.0f;
            s_W[pbin][2] = 0.0f; s_W[pbin][3] = 0.0f;
            s_W[pbin][lo0 - xb] += va0 * (1.0f - fr0);
            s_W[pbin][hi0 - xb] += va0 * fr0;
            s_W[pbin][lo1 - xb] += va1 * (1.0f - fr1);
            s_W[pbin][hi1 - xb] += va1 * fr1;
        } else {
            s_yo[pbin][0] = lo0 * NW;
            s_yo[pbin][1] = hi0 * NW;
            s_yo[pbin][2] = lo1 * NW;
            s_yo[pbin][3] = hi1 * NW;
            s_wy[pbin][0] = 0.25f * va0 * (1.0f - fr0);
            s_wy[pbin][1] = 0.25f * va0 * fr0;
            s_wy[pbin][2] = 0.25f * va1 * (1.0f - fr1);
            s_wy[pbin][3] = 0.25f * va1 * fr1;
        }
    }
    __syncthreads();

    if (t < 484) {
        const int ch  = t / 121;
        const int bin = t % 121;
        const int ph  = bin / 11, pw = bin % 11;

        const int    xb = s_xb[pw];
        const float4 W  = *(const float4*)s_W[pw];   // 16B-aligned LDS reads
        const float4 wy = *(const float4*)s_wy[ph];
        const int yo0 = s_yo[ph][0], yo1 = s_yo[ph][1];
        const int yo2 = s_yo[ph][2], yo3 = s_yo[ph][3];

        const float* fp = feat + (size_t)(b * NC + cg * GC + ch) * (NH * NW) + xb;

        // 4 independent 16B gathers (HW tolerates 4B alignment on gfx950)
        const float4 v0 = *(const float4*)(fp + yo0);
        const float4 v1 = *(const float4*)(fp + yo1);
        const float4 v2 = *(const float4*)(fp + yo2);
        const float4 v3 = *(const float4*)(fp + yo3);

        float d0 = v0.x * W.x; d0 = fmaf(v0.y, W.y, d0); d0 = fmaf(v0.z, W.z, d0); d0 = fmaf(v0.w, W.w, d0);
        float d1 = v1.x * W.x; d1 = fmaf(v1.y, W.y, d1); d1 = fmaf(v1.z, W.z, d1); d1 = fmaf(v1.w, W.w, d1);
        float d2 = v2.x * W.x; d2 = fmaf(v2.y, W.y, d2); d2 = fmaf(v2.z, W.z, d2); d2 = fmaf(v2.w, W.w, d2);
        float d3 = v3.x * W.x; d3 = fmaf(v3.y, W.y, d3); d3 = fmaf(v3.z, W.z, d3); d3 = fmaf(v3.w, W.w, d3);

        float bsum = wy.x * d0;
        bsum = fmaf(wy.y, d1, bsum);
        bsum = fmaf(wy.z, d2, bsum);
        bsum = fmaf(wy.w, d3, bsum);

        s_pool[ch][bin] = bsum;   // 0.25 already folded into wy
    }
    __syncthreads();

    if (t < 100) {
        const int ch = t / 25;
        const int r  = t % 25;
        const int oh = r / 5, ow = r % 5;
        float m = -INFINITY;
        #pragma unroll
        for (int dy = 0; dy < 3; ++dy)
            #pragma unroll
            for (int dx = 0; dx < 3; ++dx)
                m = fmaxf(m, s_pool[ch][(2 * oh + dy) * 11 + (2 * ow + dx)]);
        out[((size_t)k * NC + cg * GC) * 25 + t] = m;
    }
}

extern "C" void kernel_launch(void* const* d_in, const int* in_sizes, int n_in,
                              void* d_out, int out_size, void* d_ws, size_t ws_size,
                              hipStream_t stream) {
    const float* feat = (const float*)d_in[0];   // (4, 256, 200, 200) f32
    const float* rois = (const float*)d_in[1];   // (512, 5) f32
    float* out = (float*)d_out;                  // (512, 256, 5, 5) f32

    const int nblocks = NK * (NC / GC);          // 32768
    roi_align_maxpool<<<nblocks, 512, 0, stream>>>(feat, rois, out);
}